// Round 7
// baseline (556.375 us; speedup 1.0000x reference)
//
#include <hip/hip_runtime.h>
#include <hip/hip_bf16.h>
#include <math.h>

#define NN 2048           // x is 2048 x 2048 (DP grid = [0,2046]^2; row/col 2047 acc-only)
#define PADR 8            // zero pad rows in tab so 2-deep prefetch never goes OOB
#define NW 16             // 16 waves (4 per SIMD), single workgroup of 1024 threads
#define RPS 16            // rows per wave per step (rescale cadence, R6-proven safe)
#define SPW (NN / RPS)    // 128 active steps per wave
#define NSTEP (SPW + NW - 1)   // 143 total steps (systolic skew depth NW-1)

// ---------------------------------------------------------------------------
// Prologue: tab = exp(x) with PADR zero rows appended; fully parallel.
// ---------------------------------------------------------------------------
__global__ void exp_table_kernel(const float* __restrict__ x, float* __restrict__ tab) {
  const int n4  = (NN + PADR) * NN / 4;
  const int nx4 = NN * NN / 4;
  const float4* xv = (const float4*)x;
  float4* tv = (float4*)tab;
  for (int i = blockIdx.x * blockDim.x + threadIdx.x; i < n4; i += gridDim.x * blockDim.x) {
    float4 r = make_float4(0.f, 0.f, 0.f, 0.f);
    if (i < nx4) {
      float4 v = xv[i];
      r.x = __expf(v.x); r.y = __expf(v.y); r.z = __expf(v.z); r.w = __expf(v.w);
    }
    tv[i] = r;
  }
}

// ---------------------------------------------------------------------------
// Systolic row-sweep soft SW in exp space. 16 waves (4/SIMD), wave w owns
// columns [128w, 128w+128), lane owns 2 columns. At step s wave w does rows
// 16(s-w)..+15; the same-row left edge {S, X'} it consumes was published by
// wave w-1 LAST step (parity double-buffered) -> visible after the single
// per-step __syncthreads(). X' (gap-open units, X = cGO*X') via the Q-trick:
// Q = M1 + cGE*M0 (lane-local);  X0 = q1 + e^-2 * q2  (2 shuffles; truncation
// error e^-4 rel on X -> <=0.018 in the final log, threshold 13.1);
// X1 = fma(cGE, X0, M0);  T_j = fma(cGO, X_j, M_j);  Y = fma(cGE, Y, Tg);
// S = T + Y;  acc += es * S_diag fuses the final logsumexp numerator.
// Edge row 0 of E[] is zero-initialized and never written -> wave 0 reads
// zeros branch-free. ONE shared block exponent per step (16 rows); red[]
// parity double-buffered; escale corrects prev-parity edges. No atomics.
// ---------------------------------------------------------------------------
template<bool USE_TAB>
__global__ __launch_bounds__(NW * 64) void sw_sys_kernel(const float* __restrict__ x,
                                                         const float* __restrict__ tab,
                                                         float* __restrict__ out) {
  const int tid  = threadIdx.x;
  const int lane = tid & 63;
  const int wv   = __builtin_amdgcn_readfirstlane(tid >> 6);   // 0..15
  const int c0   = (wv << 7) + lane * 2;                       // lane's first column

  __shared__ float2 E[2][NW + 1][RPS];   // [parity][wave+1][row] = {S, X'true}; [*][0][*] = 0 forever
  __shared__ float2 dump[NW];            // write sink for lanes != 63
  __shared__ float  red[2][NW];          // [parity][wave] rescale max
  __shared__ float  wsum[NW];            // final sum

  for (int i = tid; i < 2 * (NW + 1) * RPS; i += NW * 64)
    ((float2*)E)[i] = make_float2(0.f, 0.f);
  __syncthreads();

  const float cGO = 0.006737946999085467f;   // e^-5
  const float cGE = 0.36787944117144233f;    // e^-1
  const float C2  = 0.1353352832366127f;     // e^-2

  float s1_0 = 0.f, s1_1 = 0.f;    // prev-row S (lane cols 0,1)
  float tg0  = 0.f, tg1  = 0.f;    // cGO * prev-row T
  float yc0  = 0.f, yc1  = 0.f;    // prev-row Y
  float acc = 0.f, one = 1.f, tmx = 0.f, escale = 1.f, SinC = 0.f;
  int   Etot = 0;

  const bool isL0  = (lane == 0);
  const bool isL1  = (lane == 1);
  const bool isL63 = (lane == 63);

  const float* src = (USE_TAB ? tab : x) + c0;
  float2 pfA = *(const float2*)(src);
  float2 pfB = *(const float2*)(src + NN);
  const float* pl = src + 2 * NN;      // next row to load (USE_TAB)
  int rown = 2;                        // fallback row counter

  for (int s = 0; s < NSTEP; ++s) {
    const int pr = s & 1, cr = pr ^ 1;
    const bool act = (s >= wv) && (s < wv + SPW);

    if (act) {
      float prevEdx = 0.f;
      #pragma unroll
      for (int k = 0; k < RPS; ++k) {
        // ---- row data (2-deep rolling prefetch; rows globally sequential) ----
        float2 ev;
        if (k & 1) {
          ev = pfB;
          if constexpr (USE_TAB) { pfB = *(const float2*)pl; pl += NN; }
          else { int rr = (rown < NN) ? rown : (NN - 1); pfB = *(const float2*)(src + (size_t)rr * NN); rown++; }
        } else {
          ev = pfA;
          if constexpr (USE_TAB) { pfA = *(const float2*)pl; pl += NN; }
          else { int rr = (rown < NN) ? rown : (NN - 1); pfA = *(const float2*)(src + (size_t)rr * NN); rown++; }
        }
        float ex0 = ev.x, ex1 = ev.y;
        if constexpr (!USE_TAB) { ex0 = __expf(ex0); ex1 = __expf(ex1); }

        // ---- left edge for this row (wave w-1, last step; row 0 of E = zeros) ----
        const float2 edc = E[cr][wv][k];
        const float Sr = (k == 0) ? SinC : prevEdx * escale;   // S[r-1] at left edge
        const float Xi = edc.y * escale;                       // X'[r] at left edge
        prevEdx = edc.x;

        // ---- M / acc (prev-row S shifted right one column) ----
        float sh  = __shfl_up(s1_1, 1);
        float sd0 = isL0 ? Sr : sh;
        acc = fmaf(ex0, sd0,  acc);
        acc = fmaf(ex1, s1_0, acc);
        float M0 = ex0 * (sd0  + one);
        float M1 = ex1 * (s1_0 + one);

        // ---- X' via Q-trick: Q covers 2 cols; 2-term lane seed (err e^-4) ----
        float Q  = fmaf(cGE, M0, M1);
        float q1 = __shfl_up(Q, 1);
        float q2 = __shfl_up(Q, 2);
        q2 = isL1 ? Xi : q2;
        float X0 = fmaf(C2, q2, q1);
        X0 = isL0 ? Xi : X0;
        float X1 = fmaf(cGE, X0, M0);

        // ---- T / Y / S ----
        float T0 = fmaf(cGO, X0, M0);
        float T1 = fmaf(cGO, X1, M1);
        float Y0 = fmaf(cGE, yc0, tg0);
        float Y1 = fmaf(cGE, yc1, tg1);
        float S0 = T0 + Y0, S1n = T1 + Y1;
        tmx = fmaxf(tmx, fmaxf(S0, S1n));
        tg0 = cGO * T0; tg1 = cGO * T1;
        yc0 = Y0; yc1 = Y1; s1_0 = S0; s1_1 = S1n;

        // ---- publish right edge for wave w+1 (branch-free: cndmask'd pointer) ----
        float xp = fmaf(C2, X0, Q);            // true X' at first col of wave w+1
        float2* wp = isL63 ? &E[pr][wv + 1][k] : &dump[wv];
        *wp = make_float2(S1n, xp);
      }
      SinC = prevEdx * escale;                 // row-15 edge S -> next step's row-0 diag
    }

    // ---- per-step block-wide power-of-2 rescale (16 rows) ----
    {
      float m = tmx;
      m = fmaxf(m, __shfl_xor(m, 1));
      m = fmaxf(m, __shfl_xor(m, 2));
      m = fmaxf(m, __shfl_xor(m, 4));
      m = fmaxf(m, __shfl_xor(m, 8));
      m = fmaxf(m, __shfl_xor(m, 16));
      m = fmaxf(m, __shfl_xor(m, 32));
      if (lane == 0) red[pr][wv] = m;
    }
    __syncthreads();                           // edges + red visible
    {
      float mm = red[pr][lane & 15];           // broadcast-friendly gather of 16 maxes
      mm = fmaxf(mm, __shfl_xor(mm, 1));
      mm = fmaxf(mm, __shfl_xor(mm, 2));
      mm = fmaxf(mm, __shfl_xor(mm, 4));
      mm = fmaxf(mm, __shfl_xor(mm, 8));
      tmx = 0.f;
      escale = 1.f;
      int e = (mm > 0.f) ? ilogbf(mm) : 0;
      if (e > 126) e = 126;
      if (e < -126) e = -126;
      if (e != 0) {                            // identical in every wave
        const float c = ldexpf(1.0f, -e);
        s1_0 *= c; s1_1 *= c; tg0 *= c; tg1 *= c; yc0 *= c; yc1 *= c;
        acc *= c; one *= c; SinC *= c;
        escale = c;
        Etot += e;
      }
    }
  }

  // ---- final reduction: all waves share Etot ----
  float ssum = acc;
  ssum += __shfl_xor(ssum, 1);
  ssum += __shfl_xor(ssum, 2);
  ssum += __shfl_xor(ssum, 4);
  ssum += __shfl_xor(ssum, 8);
  ssum += __shfl_xor(ssum, 16);
  ssum += __shfl_xor(ssum, 32);
  if (lane == 0) wsum[wv] = ssum;
  __syncthreads();
  if (tid == 0) {
    double tot = 0.0;
    #pragma unroll
    for (int k = 0; k < NW; ++k) tot += (double)wsum[k];
    out[0] = (float)(log(tot) + (double)Etot * 0.6931471805599453094);
  }
}

extern "C" void kernel_launch(void* const* d_in, const int* in_sizes, int n_in,
                              void* d_out, int out_size, void* d_ws, size_t ws_size,
                              hipStream_t stream) {
  const float* x = (const float*)d_in[0];
  float* out = (float*)d_out;
  float* tab = (float*)d_ws;
  const size_t need = (size_t)(NN + PADR) * NN * sizeof(float);
  if (ws_size >= need) {
    exp_table_kernel<<<1024, dim3(256), 0, stream>>>(x, tab);
    sw_sys_kernel<true><<<1, dim3(NW * 64), 0, stream>>>(x, tab, out);
  } else {
    sw_sys_kernel<false><<<1, dim3(NW * 64), 0, stream>>>(x, nullptr, out);
  }
}

// Round 11
// 345.888 us; speedup vs baseline: 1.6085x; 1.6085x over previous
//
#include <hip/hip_runtime.h>
#include <hip/hip_bf16.h>
#include <math.h>

#define NN 2048           // x is 2048 x 2048 (DP grid = [0,2046]^2)
#define TROWS 1040        // table rows per half (1024 + prefetch margin)
#define RPS 16            // rows per wave per step (R5-R7-proven rescale cadence)
#define LN2 0.6931471805599453

// d_ws layout (floats): tab[TROWS][NN] | tabR[TROWS][NN] | arr: S_fin,tg_fin,yc_fin,gM_fin,gY_fin (5*NN) | res (4 words)

// ---------------------------------------------------------------------------
// Prologue: tab[t][c] = exp(x[t][c])  (rows 0..1039, all real);
//           tabR[t][c] = exp(x[2048-t][2048-c]) or 0 when OOB (row t=0 and
//           col c=0 are zero) -- the column-mirrored, row-reversed table the
//           backward (adjoint) sweep reads with unit-stride ascending walks.
// ---------------------------------------------------------------------------
__global__ void prep_kernel(const float* __restrict__ x, float* __restrict__ tab,
                            float* __restrict__ tabR) {
  const int c = blockIdx.x * 256 + threadIdx.x;   // 0..2047
  const int t = blockIdx.y;                       // 0..TROWS-1
  tab[(size_t)t * NN + c] = __expf(x[(size_t)t * NN + c]);
  const int rr = 2048 - t, cc = 2048 - c;
  float v = 0.f;
  if (rr < 2048 && cc < 2048) v = __expf(x[(size_t)rr * NN + cc]);
  tabR[(size_t)t * NN + c] = v;
}

// ---------------------------------------------------------------------------
// MODE 1, blockIdx 0: FORWARD top half (rows 0..1023) -- the R7-proven
//   systolic sweep (16 waves, 2 cols/lane, parity LDS edges, one barrier and
//   one shared power-of-2 exponent per 16 rows). Ends by writing the boundary
//   state S[1023,b], cGO*T[1023,b], Y[1023,b] (units 2^E0) + acc_top, E0.
// MODE 1, blockIdx 1: BACKWARD adjoint of the bottom half (rows 2047->1024),
//   column-mirrored (c = 2047-b) so the code is a clone of the forward:
//     alpha = es[a+1,b+1]*(one + gM[a+1,b+1])   (diag shift = shfl_up, edges)
//     gY[a] = cGE*gY[a+1] + alpha ;  gTs = cGO*gY[a+1] + alpha
//     gX[c] = gTs + cGE*gX[c-1] (3-term truncated seed) ; gM = gTs + cGO*gX
//     accB += es[a+1,.]*gM[a+1,.]  (the zero-boundary bottom total)
//   plus one epilogue row (es row 1024) and final writes gM[1024,b], gY[1024,b]
//   (units 2^E1) + acc_b0, E1.  The two WGs are fully independent.
// MODE 0: fallback single-WG full sweep reading x directly (R7 clone).
// ---------------------------------------------------------------------------
template<int MODE>
__global__ __launch_bounds__(1024)
void sw2_kernel(const float* __restrict__ x, const float* __restrict__ tab,
                const float* __restrict__ tabR, float* __restrict__ arr,
                float* __restrict__ out) {
  const int tid  = threadIdx.x;
  const int lane = tid & 63;
  const int wv   = __builtin_amdgcn_readfirstlane(tid >> 6);   // 0..15
  const int c0   = (wv << 7) + lane * 2;

  __shared__ float2 E[2][17][RPS];   // [parity][wave+1][row]; row 0 = zero boundary
  __shared__ float2 dump[16];        // LDS write sink for lanes != 63
  __shared__ float  red[2][16];
  __shared__ float  wsum[16];

  for (int i = tid; i < 2 * 17 * RPS; i += 1024)
    ((float2*)E)[i] = make_float2(0.f, 0.f);
  __syncthreads();

  const float cGO = 0.006737946999085467f;   // e^-5
  const float cGE = 0.36787944117144233f;    // e^-1
  const float C2  = 0.1353352832366127f;     // e^-2
  const float C4  = 0.01831563888873418f;    // e^-4
  const bool isL0 = (lane == 0), isL1 = (lane == 1), isL2 = (lane == 2), isL63 = (lane == 63);

  if (MODE == 0 || blockIdx.x == 0) {
    // ======================= FORWARD =======================
    const int SPW   = (MODE == 0) ? 128 : 64;
    const int NSTEP = SPW + 15;
    float s1_0=0.f, s1_1=0.f, tg0=0.f, tg1=0.f, yc0=0.f, yc1=0.f;
    float acc=0.f, one=1.f, tmx=0.f, escale=1.f, SinC=0.f;
    int Etot = 0;
    const float* src = ((MODE == 0) ? x : tab) + c0;
    float2 pfA = *(const float2*)(src);
    float2 pfB = *(const float2*)(src + NN);
    const float* pl = src + 2 * NN;
    int rown = 2;

    for (int s = 0; s < NSTEP; ++s) {
      const int pr = s & 1, cr = pr ^ 1;
      const bool act = (s >= wv) && (s < wv + SPW);
      if (act) {
        float prevEdx = 0.f;
        #pragma unroll
        for (int k = 0; k < RPS; ++k) {
          float2 ev;
          if (k & 1) { ev = pfB;
            if (MODE == 1) { pfB = *(const float2*)pl; pl += NN; }
            else { int rr = (rown < NN) ? rown : NN - 1; pfB = *(const float2*)(src + (size_t)rr * NN); rown++; }
          } else { ev = pfA;
            if (MODE == 1) { pfA = *(const float2*)pl; pl += NN; }
            else { int rr = (rown < NN) ? rown : NN - 1; pfA = *(const float2*)(src + (size_t)rr * NN); rown++; }
          }
          float ex0 = ev.x, ex1 = ev.y;
          if (MODE == 0) { ex0 = __expf(ex0); ex1 = __expf(ex1); }

          const float2 edc = E[cr][wv][k];
          const float Sr = (k == 0) ? SinC : prevEdx * escale;
          const float Xi = edc.y * escale;
          prevEdx = edc.x;

          float sh  = __shfl_up(s1_1, 1);
          float sd0 = isL0 ? Sr : sh;
          acc = fmaf(ex0, sd0,  acc);
          acc = fmaf(ex1, s1_0, acc);
          float M0 = ex0 * (sd0  + one);
          float M1 = ex1 * (s1_0 + one);

          float Q  = fmaf(cGE, M0, M1);
          float q1 = __shfl_up(Q, 1), q2 = __shfl_up(Q, 2), q3 = __shfl_up(Q, 3);
          q2 = isL1 ? Xi : q2;
          q3 = isL2 ? Xi : (isL1 ? 0.f : q3);
          float X0 = fmaf(C4, q3, fmaf(C2, q2, q1));
          X0 = isL0 ? Xi : X0;
          float X1 = fmaf(cGE, X0, M0);

          float T0 = fmaf(cGO, X0, M0);
          float T1 = fmaf(cGO, X1, M1);
          float Y0 = fmaf(cGE, yc0, tg0);
          float Y1 = fmaf(cGE, yc1, tg1);
          float S0 = T0 + Y0, S1n = T1 + Y1;
          tmx = fmaxf(tmx, fmaxf(S0, S1n));
          tg0 = cGO * T0; tg1 = cGO * T1;
          yc0 = Y0; yc1 = Y1; s1_0 = S0; s1_1 = S1n;

          float xp = fmaf(C2, X0, Q);
          float2* wp = isL63 ? &E[pr][wv + 1][k] : &dump[wv];
          *wp = make_float2(S1n, xp);
        }
        SinC = prevEdx * escale;
      }
      { // per-step shared-exponent rescale (16 rows)
        float m = tmx;
        m = fmaxf(m, __shfl_xor(m, 1));  m = fmaxf(m, __shfl_xor(m, 2));
        m = fmaxf(m, __shfl_xor(m, 4));  m = fmaxf(m, __shfl_xor(m, 8));
        m = fmaxf(m, __shfl_xor(m, 16)); m = fmaxf(m, __shfl_xor(m, 32));
        if (lane == 0) red[pr][wv] = m;
      }
      __syncthreads();
      {
        float mm = red[pr][lane & 15];
        mm = fmaxf(mm, __shfl_xor(mm, 1)); mm = fmaxf(mm, __shfl_xor(mm, 2));
        mm = fmaxf(mm, __shfl_xor(mm, 4)); mm = fmaxf(mm, __shfl_xor(mm, 8));
        tmx = 0.f; escale = 1.f;
        int e = (mm > 0.f) ? ilogbf(mm) : 0;
        if (e > 126) e = 126; if (e < -126) e = -126;
        if (e != 0) {
          const float c = ldexpf(1.f, -e);
          s1_0 *= c; s1_1 *= c; tg0 *= c; tg1 *= c; yc0 *= c; yc1 *= c;
          acc *= c; one *= c; SinC *= c;
          escale = c; Etot += e;
        }
      }
    }
    float ssum = acc;
    ssum += __shfl_xor(ssum, 1);  ssum += __shfl_xor(ssum, 2);
    ssum += __shfl_xor(ssum, 4);  ssum += __shfl_xor(ssum, 8);
    ssum += __shfl_xor(ssum, 16); ssum += __shfl_xor(ssum, 32);
    if (lane == 0) wsum[wv] = ssum;
    __syncthreads();
    if (MODE == 0) {
      if (tid == 0) {
        double tot = 0.0;
        #pragma unroll
        for (int k = 0; k < 16; ++k) tot += (double)wsum[k];
        out[0] = (float)(log(tot) + (double)Etot * LN2);
      }
    } else {
      *(float2*)(arr + c0)          = make_float2(s1_0, s1_1);   // S[1023,b]
      *(float2*)(arr + NN + c0)     = make_float2(tg0, tg1);     // cGO*T[1023,b]
      *(float2*)(arr + 2 * NN + c0) = make_float2(yc0, yc1);     // Y[1023,b]
      if (tid == 0) {
        float t = 0.f;
        #pragma unroll
        for (int k = 0; k < 16; ++k) t += wsum[k];
        arr[5 * NN + 0] = t;                     // acc_top   (units 2^E0)
        ((int*)(arr + 5 * NN))[2] = Etot;        // E0
      }
    }
  } else {
    // ======================= BACKWARD (adjoint, mirrored cols) =======================
    float gM1_0=0.f, gM1_1=0.f, gY1_0=0.f, gY1_1=0.f;
    float accB=0.f, one=1.f, tmx=0.f, escale=1.f, gMinC=0.f;
    int Etot = 0;
    const float* src = tabR + c0;
    float2 pfA = *(const float2*)(src);
    float2 pfB = *(const float2*)(src + NN);
    const float* pl = src + 2 * NN;

    const int NSTEPB = 64 + 15 + 1;              // +1: epilogue row (es row 1024)
    for (int s = 0; s < NSTEPB; ++s) {
      const int pr = s & 1, cr = pr ^ 1;
      const bool actM = (s >= wv) && (s < wv + 64);
      const bool actE = (s == wv + 64);
      if (actM) {
        float prevEdx = 0.f;
        #pragma unroll
        for (int k = 0; k < RPS; ++k) {
          float2 ev;
          if (k & 1) { ev = pfB; pfB = *(const float2*)pl; pl += NN; }
          else       { ev = pfA; pfA = *(const float2*)pl; pl += NN; }
          const float er0 = ev.x, er1 = ev.y;    // es[a+1, 2048-c]

          const float2 edc = E[cr][wv][k];
          const float gMdIn = (k == 0) ? gMinC : prevEdx * escale;
          const float Xi = edc.y * escale;
          prevEdx = edc.x;

          float gmh  = __shfl_up(gM1_1, 1);
          float gMd0 = isL0 ? gMdIn : gmh;       // gM[a+1, b+1]
          float gMd1 = gM1_0;
          accB = fmaf(er0, gMd0, accB);          // acc_b0 = sum es*gM
          accB = fmaf(er1, gMd1, accB);
          float a0 = er0 * (gMd0 + one);         // alpha
          float a1 = er1 * (gMd1 + one);

          float gY0n = fmaf(cGE, gY1_0, a0);
          float gY1n = fmaf(cGE, gY1_1, a1);
          float gTs0 = fmaf(cGO, gY1_0, a0);
          float gTs1 = fmaf(cGO, gY1_1, a1);

          float Qg = fmaf(cGE, gTs0, gTs1);
          float q1 = __shfl_up(Qg, 1), q2 = __shfl_up(Qg, 2), q3 = __shfl_up(Qg, 3);
          q2 = isL1 ? Xi : q2;
          q3 = isL2 ? Xi : (isL1 ? 0.f : q3);
          float gXin = fmaf(C4, q3, fmaf(C2, q2, q1));
          gXin = isL0 ? Xi : gXin;
          float gX0  = fmaf(cGE, gXin, gTs0);
          float gM0n = fmaf(cGO, gXin, gTs0);
          float gM1n = fmaf(cGO, gX0,  gTs1);

          tmx = fmaxf(tmx, fmaxf(fmaxf(gM0n, gM1n), fmaxf(gY0n, gY1n)));
          gM1_0 = gM0n; gM1_1 = gM1n; gY1_0 = gY0n; gY1_1 = gY1n;

          float xg = fmaf(C2, gXin, Qg);         // gX entering next wave
          float2* wp = isL63 ? &E[pr][wv + 1][k] : &dump[wv];
          *wp = make_float2(gM1n, xg);
        }
        gMinC = prevEdx * escale;
      } else if (actE) {
        // epilogue: accB += es[1024, .] * gM[1024, .]  (tabR row 1024 = pfA)
        const float er0 = pfA.x, er1 = pfA.y;
        float gmh  = __shfl_up(gM1_1, 1);
        float gMd0 = isL0 ? gMinC : gmh;
        float gMd1 = gM1_0;
        accB = fmaf(er0, gMd0, accB);
        accB = fmaf(er1, gMd1, accB);
      }
      { // rescale (identical machinery; carries stay live to the end)
        float m = tmx;
        m = fmaxf(m, __shfl_xor(m, 1));  m = fmaxf(m, __shfl_xor(m, 2));
        m = fmaxf(m, __shfl_xor(m, 4));  m = fmaxf(m, __shfl_xor(m, 8));
        m = fmaxf(m, __shfl_xor(m, 16)); m = fmaxf(m, __shfl_xor(m, 32));
        if (lane == 0) red[pr][wv] = m;
      }
      __syncthreads();
      {
        float mm = red[pr][lane & 15];
        mm = fmaxf(mm, __shfl_xor(mm, 1)); mm = fmaxf(mm, __shfl_xor(mm, 2));
        mm = fmaxf(mm, __shfl_xor(mm, 4)); mm = fmaxf(mm, __shfl_xor(mm, 8));
        tmx = 0.f; escale = 1.f;
        int e = (mm > 0.f) ? ilogbf(mm) : 0;
        if (e > 126) e = 126; if (e < -126) e = -126;
        if (e != 0) {
          const float c = ldexpf(1.f, -e);
          gM1_0 *= c; gM1_1 *= c; gY1_0 *= c; gY1_1 *= c;
          accB *= c; one *= c; gMinC *= c;
          escale = c; Etot += e;
        }
      }
    }
    // write gM[1024,b], gY[1024,b] (b = 2047-c mirrored -> descending pair)
    *(float2*)(arr + 3 * NN + (2046 - c0)) = make_float2(gM1_1, gM1_0);
    *(float2*)(arr + 4 * NN + (2046 - c0)) = make_float2(gY1_1, gY1_0);
    float ssum = accB;
    ssum += __shfl_xor(ssum, 1);  ssum += __shfl_xor(ssum, 2);
    ssum += __shfl_xor(ssum, 4);  ssum += __shfl_xor(ssum, 8);
    ssum += __shfl_xor(ssum, 16); ssum += __shfl_xor(ssum, 32);
    if (lane == 0) wsum[wv] = ssum;
    __syncthreads();
    if (tid == 0) {
      float t = 0.f;
      #pragma unroll
      for (int k = 0; k < 16; ++k) t += wsum[k];
      arr[5 * NN + 1] = t;                       // acc_b0   (units 2^E1)
      ((int*)(arr + 5 * NN))[3] = Etot;          // E1
    }
  }
}

// ---------------------------------------------------------------------------
// Combine: total = acc_top*2^E0 + acc_b0*2^E1 + <w,u>*... with three
// exponent groups:  A0  (2^E0)     = acc_top + sum_b es[1024,b+1]*S[1023,b]
//                   A1  (2^E1)     = acc_b0
//                   A01 (2^E0+E1)  = sum_b es[1024,b+1]*gM[1024,b+1]*S[1023,b]
//                                  + sum_b gY[1024,b]*(cGO*T[1023,b] + cGE*Y[1023,b])
// out = log(sum Ai * 2^(Ei - emax)) + emax*ln2   (in double; tiny groups -> 0)
// ---------------------------------------------------------------------------
__global__ __launch_bounds__(1024)
void combine_kernel(const float* __restrict__ tab, const float* __restrict__ arr,
                    float* __restrict__ out) {
  __shared__ double sh01[16], sh0[16];
  const int tid = threadIdx.x, lane = tid & 63, wv = tid >> 6;
  const float cGE = 0.36787944117144233f;
  double t01 = 0.0, t0 = 0.0;
  for (int b = tid; b < NN; b += 1024) {
    const float S  = arr[b];
    const float tg = arr[NN + b];
    const float yc = arr[2 * NN + b];
    const float gY = arr[4 * NN + b];
    t01 += (double)gY * ((double)tg + (double)cGE * (double)yc);
    if (b < NN - 1) {
      const float es = tab[(size_t)1024 * NN + b + 1];
      const float gM = arr[3 * NN + b + 1];
      t01 += (double)es * (double)gM * (double)S;
      t0  += (double)es * (double)S;
    }
  }
  #pragma unroll
  for (int off = 1; off < 64; off <<= 1) {
    t01 += __shfl_xor(t01, off);
    t0  += __shfl_xor(t0, off);
  }
  if (lane == 0) { sh01[wv] = t01; sh0[wv] = t0; }
  __syncthreads();
  if (tid == 0) {
    double A01 = 0.0, A0 = 0.0;
    #pragma unroll
    for (int k = 0; k < 16; ++k) { A01 += sh01[k]; A0 += sh0[k]; }
    const float* resF = arr + 5 * NN;
    const float accTop = resF[0], accB = resF[1];
    const int E0 = ((const int*)resF)[2], E1 = ((const int*)resF)[3];
    A0 += (double)accTop;
    const double A1 = (double)accB;
    const long long e01 = (long long)E0 + (long long)E1;
    long long em = e01;
    if ((long long)E0 > em) em = E0;
    if ((long long)E1 > em) em = E1;
    const double tot = A01 * exp2((double)(e01 - em))
                     + A0  * exp2((double)((long long)E0 - em))
                     + A1  * exp2((double)((long long)E1 - em));
    out[0] = (float)(log(tot) + (double)em * LN2);
  }
}

extern "C" void kernel_launch(void* const* d_in, const int* in_sizes, int n_in,
                              void* d_out, int out_size, void* d_ws, size_t ws_size,
                              hipStream_t stream) {
  const float* x = (const float*)d_in[0];
  float* out = (float*)d_out;
  const size_t need = ((size_t)2 * TROWS * NN + 5 * NN + 16) * sizeof(float);
  if (ws_size >= need) {
    float* tab  = (float*)d_ws;
    float* tabR = tab + (size_t)TROWS * NN;
    float* arr  = tab + (size_t)2 * TROWS * NN;
    prep_kernel<<<dim3(NN / 256, TROWS), dim3(256), 0, stream>>>(x, tab, tabR);
    sw2_kernel<1><<<dim3(2), dim3(1024), 0, stream>>>(x, tab, tabR, arr, out);
    combine_kernel<<<dim3(1), dim3(1024), 0, stream>>>(tab, arr, out);
  } else {
    sw2_kernel<0><<<dim3(1), dim3(1024), 0, stream>>>(x, nullptr, nullptr, nullptr, out);
  }
}

// Round 12
// 285.768 us; speedup vs baseline: 1.9469x; 1.2104x over previous
//
#include <hip/hip_runtime.h>
#include <hip/hip_bf16.h>
#include <math.h>

#define NN 2048           // x is 2048 x 2048 (DP grid = [0,2046]^2)
#define TROWS 1040        // table rows per half (1024 + prefetch margin)
#define NW 8              // 8 waves per WG (2 per SIMD), CPL=4
#define RPS 16            // rows per wave per step (proven rescale cadence)
#define LN2 0.6931471805599453

// d_ws layout (floats): tab[TROWS][NN] | tabR[TROWS][NN] | arr: S,tg,yc,gM,gY (5*NN) | res (4 words)

// ---------------------------------------------------------------------------
// Prologue: tab[t][c] = exp(x[t][c]); tabR[t][c] = exp(x[2048-t][2048-c]) or 0
// when OOB -- the column-mirrored, row-reversed table for the adjoint sweep.
// ---------------------------------------------------------------------------
__global__ void prep_kernel(const float* __restrict__ x, float* __restrict__ tab,
                            float* __restrict__ tabR) {
  const int c = blockIdx.x * 256 + threadIdx.x;
  const int t = blockIdx.y;
  tab[(size_t)t * NN + c] = __expf(x[(size_t)t * NN + c]);
  const int rr = 2048 - t, cc = 2048 - c;
  float v = 0.f;
  if (rr < 2048 && cc < 2048) v = __expf(x[(size_t)rr * NN + cc]);
  tabR[(size_t)t * NN + c] = v;
}

// ---------------------------------------------------------------------------
// MODE 1, blockIdx 0: FORWARD top half (rows 0..1023). 8 waves, 4 cols/lane,
//   systolic skew (wave w does rows 16(s-w)..+15 at step s), parity LDS edges
//   {S, X'}, one barrier + one shared pow2 exponent per 16 rows.
//   X' via CPL4 Q-trick: Q = M3+cGE*M2+cGE^2*M1+cGE^3*M0 (Horner);
//   X0 = q1 + e^-4*q2 (2 shuffles, e^-8 truncation -- R6-proven depth);
//   X_{j+1} = fma(cGE,X_j,M_j); T_j = fma(cGO,X_j,M_j); Y = fma(cGE,Y,Tg);
//   acc += es*S_diag. Ends writing boundary S,cGO*T,Y at row 1023 + acc,E0.
// MODE 1, blockIdx 1: BACKWARD adjoint of rows 2047->1024, column-mirrored
//   (clone structure; alpha = es*(gM_diag+one), gY/gTs column recurrences,
//   same Q-trick scan, accB += es*gM). Ends writing gM,gY at row 1024 + acc,E1.
// MODE 0: fallback single-WG full sweep reading x directly.
// ---------------------------------------------------------------------------
template<int MODE>
__global__ __launch_bounds__(NW * 64)
void sw2_kernel(const float* __restrict__ x, const float* __restrict__ tab,
                const float* __restrict__ tabR, float* __restrict__ arr,
                float* __restrict__ out) {
  const int tid  = threadIdx.x;
  const int lane = tid & 63;
  const int wv   = __builtin_amdgcn_readfirstlane(tid >> 6);   // 0..7
  const int c0   = (wv << 8) + lane * 4;

  __shared__ float2 E[2][NW + 1][RPS];   // [parity][wave+1][row]; wave-0 input = zeros
  __shared__ float  red[2][NW];
  __shared__ float  wsum[NW];

  for (int i = tid; i < 2 * (NW + 1) * RPS; i += NW * 64)
    ((float2*)E)[i] = make_float2(0.f, 0.f);
  __syncthreads();

  const float cGO = 0.006737946999085467f;   // e^-5
  const float cGE = 0.36787944117144233f;    // e^-1
  const float C4  = 0.01831563888873418f;    // e^-4
  const bool isL0 = (lane == 0), isL1 = (lane == 1), isL63 = (lane == 63);

  if (MODE == 0 || blockIdx.x == 0) {
    // ======================= FORWARD =======================
    const int SPW   = (MODE == 0) ? 128 : 64;
    const int NSTEP = SPW + NW - 1;
    float s1_0=0.f,s1_1=0.f,s1_2=0.f,s1_3=0.f;
    float tg0=0.f,tg1=0.f,tg2=0.f,tg3=0.f;
    float yc0=0.f,yc1=0.f,yc2=0.f,yc3=0.f;
    float acc=0.f, one=1.f, tmx=0.f, escale=1.f, SinC=0.f;
    int Etot = 0;
    const float* src = ((MODE == 0) ? x : tab) + c0;
    float4 pfA = *(const float4*)(src);
    float4 pfB = *(const float4*)(src + NN);
    const float* pl = src + 2 * NN;
    int rown = 2;

    for (int s = 0; s < NSTEP; ++s) {
      const int pr = s & 1, cr = pr ^ 1;
      const bool act = (s >= wv) && (s < wv + SPW);
      if (act) {
        float prevEdx = 0.f;
        #pragma unroll
        for (int k = 0; k < RPS; ++k) {
          float4 ev;
          if (k & 1) { ev = pfB;
            if (MODE == 1) { pfB = *(const float4*)pl; pl += NN; }
            else { int rr = (rown < NN) ? rown : NN - 1; pfB = *(const float4*)(src + (size_t)rr * NN); rown++; }
          } else { ev = pfA;
            if (MODE == 1) { pfA = *(const float4*)pl; pl += NN; }
            else { int rr = (rown < NN) ? rown : NN - 1; pfA = *(const float4*)(src + (size_t)rr * NN); rown++; }
          }
          float ex0 = ev.x, ex1 = ev.y, ex2 = ev.z, ex3 = ev.w;
          if (MODE == 0) { ex0 = __expf(ex0); ex1 = __expf(ex1); ex2 = __expf(ex2); ex3 = __expf(ex3); }

          const float2 edc = E[cr][wv][k];
          const float Sr = (k == 0) ? SinC : prevEdx * escale;
          const float Xi = edc.y * escale;
          prevEdx = edc.x;

          float sh  = __shfl_up(s1_3, 1);
          float sd0 = isL0 ? Sr : sh;
          acc = fmaf(ex0, sd0,  acc);
          acc = fmaf(ex1, s1_0, acc);
          acc = fmaf(ex2, s1_1, acc);
          acc = fmaf(ex3, s1_2, acc);
          float M0 = ex0 * (sd0  + one);
          float M1 = ex1 * (s1_0 + one);
          float M2 = ex2 * (s1_1 + one);
          float M3 = ex3 * (s1_2 + one);

          float Q  = fmaf(cGE, fmaf(cGE, fmaf(cGE, M0, M1), M2), M3);
          float q1 = __shfl_up(Q, 1);
          float q2 = __shfl_up(Q, 2);
          q2 = isL1 ? Xi : q2;
          float X0 = fmaf(C4, q2, q1);
          X0 = isL0 ? Xi : X0;
          float X1 = fmaf(cGE, X0, M0);
          float X2 = fmaf(cGE, X1, M1);
          float X3 = fmaf(cGE, X2, M2);

          float T0 = fmaf(cGO, X0, M0);
          float T1 = fmaf(cGO, X1, M1);
          float T2 = fmaf(cGO, X2, M2);
          float T3 = fmaf(cGO, X3, M3);
          float Y0 = fmaf(cGE, yc0, tg0);
          float Y1 = fmaf(cGE, yc1, tg1);
          float Y2 = fmaf(cGE, yc2, tg2);
          float Y3 = fmaf(cGE, yc3, tg3);
          float S0 = T0 + Y0, S1n = T1 + Y1, S2n = T2 + Y2, S3n = T3 + Y3;
          tmx = fmaxf(tmx, fmaxf(fmaxf(S0, S1n), fmaxf(S2n, S3n)));
          tg0 = cGO * T0; tg1 = cGO * T1; tg2 = cGO * T2; tg3 = cGO * T3;
          yc0 = Y0; yc1 = Y1; yc2 = Y2; yc3 = Y3;
          s1_0 = S0; s1_1 = S1n; s1_2 = S2n; s1_3 = S3n;

          if (isL63) E[pr][wv + 1][k] = make_float2(S3n, fmaf(C4, X0, Q));
        }
        SinC = prevEdx * escale;
      }
      { // per-step shared-exponent rescale (16 rows)
        float m = tmx;
        m = fmaxf(m, __shfl_xor(m, 1));  m = fmaxf(m, __shfl_xor(m, 2));
        m = fmaxf(m, __shfl_xor(m, 4));  m = fmaxf(m, __shfl_xor(m, 8));
        m = fmaxf(m, __shfl_xor(m, 16)); m = fmaxf(m, __shfl_xor(m, 32));
        if (lane == 0) red[pr][wv] = m;
      }
      __syncthreads();
      {
        float mm = red[pr][lane & (NW - 1)];
        mm = fmaxf(mm, __shfl_xor(mm, 1));
        mm = fmaxf(mm, __shfl_xor(mm, 2));
        mm = fmaxf(mm, __shfl_xor(mm, 4));
        tmx = 0.f; escale = 1.f;
        int e = (mm > 0.f) ? ilogbf(mm) : 0;
        if (e > 126) e = 126; if (e < -126) e = -126;
        if (e != 0) {
          const float c = ldexpf(1.f, -e);
          s1_0*=c; s1_1*=c; s1_2*=c; s1_3*=c;
          tg0*=c; tg1*=c; tg2*=c; tg3*=c;
          yc0*=c; yc1*=c; yc2*=c; yc3*=c;
          acc*=c; one*=c; SinC*=c;
          escale = c; Etot += e;
        }
      }
    }
    float ssum = acc;
    ssum += __shfl_xor(ssum, 1);  ssum += __shfl_xor(ssum, 2);
    ssum += __shfl_xor(ssum, 4);  ssum += __shfl_xor(ssum, 8);
    ssum += __shfl_xor(ssum, 16); ssum += __shfl_xor(ssum, 32);
    if (lane == 0) wsum[wv] = ssum;
    __syncthreads();
    if (MODE == 0) {
      if (tid == 0) {
        double tot = 0.0;
        #pragma unroll
        for (int k = 0; k < NW; ++k) tot += (double)wsum[k];
        out[0] = (float)(log(tot) + (double)Etot * LN2);
      }
    } else {
      *(float4*)(arr + c0)          = make_float4(s1_0, s1_1, s1_2, s1_3);  // S[1023,b]
      *(float4*)(arr + NN + c0)     = make_float4(tg0, tg1, tg2, tg3);      // cGO*T[1023,b]
      *(float4*)(arr + 2 * NN + c0) = make_float4(yc0, yc1, yc2, yc3);      // Y[1023,b]
      if (tid == 0) {
        float t = 0.f;
        #pragma unroll
        for (int k = 0; k < NW; ++k) t += wsum[k];
        arr[5 * NN + 0] = t;                     // acc_top (units 2^E0)
        ((int*)(arr + 5 * NN))[2] = Etot;        // E0
      }
    }
  } else {
    // ======================= BACKWARD (adjoint, mirrored cols) =======================
    float gM1_0=0.f,gM1_1=0.f,gM1_2=0.f,gM1_3=0.f;
    float gY1_0=0.f,gY1_1=0.f,gY1_2=0.f,gY1_3=0.f;
    float accB=0.f, one=1.f, tmx=0.f, escale=1.f, gMinC=0.f;
    int Etot = 0;
    const float* src = tabR + c0;
    float4 pfA = *(const float4*)(src);
    float4 pfB = *(const float4*)(src + NN);
    const float* pl = src + 2 * NN;

    const int NSTEPB = 64 + NW - 1 + 1;          // +1: epilogue row (es row 1024)
    for (int s = 0; s < NSTEPB; ++s) {
      const int pr = s & 1, cr = pr ^ 1;
      const bool actM = (s >= wv) && (s < wv + 64);
      const bool actE = (s == wv + 64);
      if (actM) {
        float prevEdx = 0.f;
        #pragma unroll
        for (int k = 0; k < RPS; ++k) {
          float4 ev;
          if (k & 1) { ev = pfB; pfB = *(const float4*)pl; pl += NN; }
          else       { ev = pfA; pfA = *(const float4*)pl; pl += NN; }
          const float er0 = ev.x, er1 = ev.y, er2 = ev.z, er3 = ev.w;

          const float2 edc = E[cr][wv][k];
          const float gMdIn = (k == 0) ? gMinC : prevEdx * escale;
          const float Xi = edc.y * escale;
          prevEdx = edc.x;

          float gmh  = __shfl_up(gM1_3, 1);
          float gMd0 = isL0 ? gMdIn : gmh;
          float gMd1 = gM1_0, gMd2 = gM1_1, gMd3 = gM1_2;
          accB = fmaf(er0, gMd0, accB);
          accB = fmaf(er1, gMd1, accB);
          accB = fmaf(er2, gMd2, accB);
          accB = fmaf(er3, gMd3, accB);
          float a0 = er0 * (gMd0 + one);
          float a1 = er1 * (gMd1 + one);
          float a2 = er2 * (gMd2 + one);
          float a3 = er3 * (gMd3 + one);

          float gTs0 = fmaf(cGO, gY1_0, a0);
          float gTs1 = fmaf(cGO, gY1_1, a1);
          float gTs2 = fmaf(cGO, gY1_2, a2);
          float gTs3 = fmaf(cGO, gY1_3, a3);
          float gY0n = fmaf(cGE, gY1_0, a0);
          float gY1n = fmaf(cGE, gY1_1, a1);
          float gY2n = fmaf(cGE, gY1_2, a2);
          float gY3n = fmaf(cGE, gY1_3, a3);

          float Qg = fmaf(cGE, fmaf(cGE, fmaf(cGE, gTs0, gTs1), gTs2), gTs3);
          float q1 = __shfl_up(Qg, 1);
          float q2 = __shfl_up(Qg, 2);
          q2 = isL1 ? Xi : q2;
          float gXin = fmaf(C4, q2, q1);
          gXin = isL0 ? Xi : gXin;
          float gX0 = fmaf(cGE, gXin, gTs0);
          float gX1 = fmaf(cGE, gX0,  gTs1);
          float gX2 = fmaf(cGE, gX1,  gTs2);
          float gM0n = fmaf(cGO, gXin, gTs0);
          float gM1n = fmaf(cGO, gX0,  gTs1);
          float gM2n = fmaf(cGO, gX1,  gTs2);
          float gM3n = fmaf(cGO, gX2,  gTs3);

          tmx = fmaxf(tmx, fmaxf(fmaxf(gM0n, gM1n), fmaxf(gM2n, gM3n)));
          tmx = fmaxf(tmx, fmaxf(fmaxf(gY0n, gY1n), fmaxf(gY2n, gY3n)));
          gM1_0 = gM0n; gM1_1 = gM1n; gM1_2 = gM2n; gM1_3 = gM3n;
          gY1_0 = gY0n; gY1_1 = gY1n; gY1_2 = gY2n; gY1_3 = gY3n;

          if (isL63) E[pr][wv + 1][k] = make_float2(gM3n, fmaf(C4, gXin, Qg));
        }
        gMinC = prevEdx * escale;
      } else if (actE) {
        // epilogue: accB += es[1024,.] * gM[1024,.]  (tabR row 1024 = pfA)
        float gmh  = __shfl_up(gM1_3, 1);
        float gMd0 = isL0 ? gMinC : gmh;
        accB = fmaf(pfA.x, gMd0,  accB);
        accB = fmaf(pfA.y, gM1_0, accB);
        accB = fmaf(pfA.z, gM1_1, accB);
        accB = fmaf(pfA.w, gM1_2, accB);
      }
      { // rescale (carries stay live to the end)
        float m = tmx;
        m = fmaxf(m, __shfl_xor(m, 1));  m = fmaxf(m, __shfl_xor(m, 2));
        m = fmaxf(m, __shfl_xor(m, 4));  m = fmaxf(m, __shfl_xor(m, 8));
        m = fmaxf(m, __shfl_xor(m, 16)); m = fmaxf(m, __shfl_xor(m, 32));
        if (lane == 0) red[pr][wv] = m;
      }
      __syncthreads();
      {
        float mm = red[pr][lane & (NW - 1)];
        mm = fmaxf(mm, __shfl_xor(mm, 1));
        mm = fmaxf(mm, __shfl_xor(mm, 2));
        mm = fmaxf(mm, __shfl_xor(mm, 4));
        tmx = 0.f; escale = 1.f;
        int e = (mm > 0.f) ? ilogbf(mm) : 0;
        if (e > 126) e = 126; if (e < -126) e = -126;
        if (e != 0) {
          const float c = ldexpf(1.f, -e);
          gM1_0*=c; gM1_1*=c; gM1_2*=c; gM1_3*=c;
          gY1_0*=c; gY1_1*=c; gY1_2*=c; gY1_3*=c;
          accB*=c; one*=c; gMinC*=c;
          escale = c; Etot += e;
        }
      }
    }
    // write gM[1024,b], gY[1024,b]  (b = 2047-c -> reversed float4)
    *(float4*)(arr + 3 * NN + (2044 - c0)) = make_float4(gM1_3, gM1_2, gM1_1, gM1_0);
    *(float4*)(arr + 4 * NN + (2044 - c0)) = make_float4(gY1_3, gY1_2, gY1_1, gY1_0);
    float ssum = accB;
    ssum += __shfl_xor(ssum, 1);  ssum += __shfl_xor(ssum, 2);
    ssum += __shfl_xor(ssum, 4);  ssum += __shfl_xor(ssum, 8);
    ssum += __shfl_xor(ssum, 16); ssum += __shfl_xor(ssum, 32);
    if (lane == 0) wsum[wv] = ssum;
    __syncthreads();
    if (tid == 0) {
      float t = 0.f;
      #pragma unroll
      for (int k = 0; k < NW; ++k) t += wsum[k];
      arr[5 * NN + 1] = t;                       // acc_b0 (units 2^E1)
      ((int*)(arr + 5 * NN))[3] = Etot;          // E1
    }
  }
}

// ---------------------------------------------------------------------------
// Combine (unchanged from R11): three exponent groups
//   A0 (2^E0) = acc_top + sum_b es[1024,b+1]*S[1023,b] ;  A1 (2^E1) = acc_b0
//   A01 (2^E0+E1) = sum_b es[1024,b+1]*gM[1024,b+1]*S[1023,b]
//                 + sum_b gY[1024,b]*(cGO*T[1023,b] + cGE*Y[1023,b])
// ---------------------------------------------------------------------------
__global__ __launch_bounds__(1024)
void combine_kernel(const float* __restrict__ tab, const float* __restrict__ arr,
                    float* __restrict__ out) {
  __shared__ double sh01[16], sh0[16];
  const int tid = threadIdx.x, lane = tid & 63, wv = tid >> 6;
  const float cGE = 0.36787944117144233f;
  double t01 = 0.0, t0 = 0.0;
  for (int b = tid; b < NN; b += 1024) {
    const float S  = arr[b];
    const float tg = arr[NN + b];
    const float yc = arr[2 * NN + b];
    const float gY = arr[4 * NN + b];
    t01 += (double)gY * ((double)tg + (double)cGE * (double)yc);
    if (b < NN - 1) {
      const float es = tab[(size_t)1024 * NN + b + 1];
      const float gM = arr[3 * NN + b + 1];
      t01 += (double)es * (double)gM * (double)S;
      t0  += (double)es * (double)S;
    }
  }
  #pragma unroll
  for (int off = 1; off < 64; off <<= 1) {
    t01 += __shfl_xor(t01, off);
    t0  += __shfl_xor(t0, off);
  }
  if (lane == 0) { sh01[wv] = t01; sh0[wv] = t0; }
  __syncthreads();
  if (tid == 0) {
    double A01 = 0.0, A0 = 0.0;
    #pragma unroll
    for (int k = 0; k < 16; ++k) { A01 += sh01[k]; A0 += sh0[k]; }
    const float* resF = arr + 5 * NN;
    const float accTop = resF[0], accB = resF[1];
    const int E0 = ((const int*)resF)[2], E1 = ((const int*)resF)[3];
    A0 += (double)accTop;
    const double A1 = (double)accB;
    const long long e01 = (long long)E0 + (long long)E1;
    long long em = e01;
    if ((long long)E0 > em) em = E0;
    if ((long long)E1 > em) em = E1;
    const double tot = A01 * exp2((double)(e01 - em))
                     + A0  * exp2((double)((long long)E0 - em))
                     + A1  * exp2((double)((long long)E1 - em));
    out[0] = (float)(log(tot) + (double)em * LN2);
  }
}

extern "C" void kernel_launch(void* const* d_in, const int* in_sizes, int n_in,
                              void* d_out, int out_size, void* d_ws, size_t ws_size,
                              hipStream_t stream) {
  const float* x = (const float*)d_in[0];
  float* out = (float*)d_out;
  const size_t need = ((size_t)2 * TROWS * NN + 5 * NN + 16) * sizeof(float);
  if (ws_size >= need) {
    float* tab  = (float*)d_ws;
    float* tabR = tab + (size_t)TROWS * NN;
    float* arr  = tab + (size_t)2 * TROWS * NN;
    prep_kernel<<<dim3(NN / 256, TROWS), dim3(256), 0, stream>>>(x, tab, tabR);
    sw2_kernel<1><<<dim3(2), dim3(NW * 64), 0, stream>>>(x, tab, tabR, arr, out);
    combine_kernel<<<dim3(1), dim3(1024), 0, stream>>>(tab, arr, out);
  } else {
    sw2_kernel<0><<<dim3(1), dim3(NW * 64), 0, stream>>>(x, nullptr, nullptr, nullptr, out);
  }
}